// Round 2
// baseline (180.510 us; speedup 1.0000x reference)
//
#include <hip/hip_runtime.h>
#include <math.h>

#define T_TOTAL 8192
#define D_TOTAL 4096
#define E 64
#define TOPK 8

#define DK 64          // K chunk per stage
#define TMW 16         // tokens per wave
#define WAVES 4
#define TB (TMW * WAVES)   // 64 tokens per block

// ---------------- Kernel 1: logits partial GEMM ----------------
// lane = expert (E == wavefront size). Each lane accumulates logits for
// TMW tokens of its expert. w fragments in registers (reused over 16 tokens),
// x read via uniform-address (broadcast) ds_read_b128 -> no LDS pressure.
// grid: (T/TB, S). Partials to part[s][t][e].
__global__ __launch_bounds__(256, 2)
void gemm_logits(const float* __restrict__ x, const float* __restrict__ w,
                 float* __restrict__ part, int dchunk) {
    __shared__ __align__(16) float xs[TB * DK];    // [t][64] linear, 16 KB
    __shared__ __align__(16) float wt[DK][65];     // transposed w chunk, padded

    const int tid  = threadIdx.x;
    const int lane = tid & 63;       // expert id
    const int wv   = tid >> 6;       // wave id -> token group
    const int tok0 = blockIdx.x * TB;
    const int d0   = blockIdx.y * dchunk;

    // staging maps
    const int wrow = tid >> 4;       // 0..15 (expert row per pass)
    const int wkc  = tid & 15;       // float4 col 0..15

    float acc[TMW];
#pragma unroll
    for (int i = 0; i < TMW; ++i) acc[i] = 0.f;

    const int nchunks = dchunk / DK;

    for (int c = 0; c < nchunks; ++c) {
        const int k0 = d0 + c * DK;
        __syncthreads();   // protect LDS before overwrite

        // ---- stage x tile: 64 tokens x 64 floats, linear, conflict-free ----
#pragma unroll
        for (int r = 0; r < 4; ++r) {
            const int f4  = r * 256 + tid;        // float4 index 0..1023
            const int row = f4 >> 4;
            const int c4  = f4 & 15;
            const float4 v = *reinterpret_cast<const float4*>(
                &x[(size_t)(tok0 + row) * D_TOTAL + k0 + c4 * 4]);
            *reinterpret_cast<float4*>(&xs[f4 * 4]) = v;
        }
        // ---- stage w chunk transposed: wt[k][e], pad 65 (2-way banks) ----
#pragma unroll
        for (int p = 0; p < 4; ++p) {
            const int e = wrow + p * 16;
            const float4 v = *reinterpret_cast<const float4*>(
                &w[(size_t)e * D_TOTAL + k0 + wkc * 4]);
            wt[wkc * 4 + 0][e] = v.x;
            wt[wkc * 4 + 1][e] = v.y;
            wt[wkc * 4 + 2][e] = v.z;
            wt[wkc * 4 + 3][e] = v.w;
        }
        __syncthreads();

        // ---- compute: 4 sub-chunks of 16 k ----
#pragma unroll
        for (int sc = 0; sc < 4; ++sc) {
            float wr[16];
#pragma unroll
            for (int kk = 0; kk < 16; ++kk)
                wr[kk] = wt[sc * 16 + kk][lane];   // consecutive-lane b32, conflict-free

#pragma unroll
            for (int t = 0; t < TMW; ++t) {
                const float* xp = &xs[(wv * TMW + t) * DK + sc * 16];  // wave-uniform addr
                const float4 a = *reinterpret_cast<const float4*>(xp);
                const float4 b = *reinterpret_cast<const float4*>(xp + 4);
                const float4 g = *reinterpret_cast<const float4*>(xp + 8);
                const float4 h = *reinterpret_cast<const float4*>(xp + 12);
                float s = acc[t];
                s = fmaf(a.x, wr[0],  s);
                s = fmaf(a.y, wr[1],  s);
                s = fmaf(a.z, wr[2],  s);
                s = fmaf(a.w, wr[3],  s);
                s = fmaf(b.x, wr[4],  s);
                s = fmaf(b.y, wr[5],  s);
                s = fmaf(b.z, wr[6],  s);
                s = fmaf(b.w, wr[7],  s);
                s = fmaf(g.x, wr[8],  s);
                s = fmaf(g.y, wr[9],  s);
                s = fmaf(g.z, wr[10], s);
                s = fmaf(g.w, wr[11], s);
                s = fmaf(h.x, wr[12], s);
                s = fmaf(h.y, wr[13], s);
                s = fmaf(h.z, wr[14], s);
                s = fmaf(h.w, wr[15], s);
                acc[t] = s;
            }
        }
    }

    // ---- write partials: part[s][tok][e], coalesced (lane = e) ----
    float* pb = part + ((size_t)blockIdx.y * T_TOTAL + tok0 + wv * TMW) * E;
#pragma unroll
    for (int t = 0; t < TMW; ++t) {
        pb[(size_t)t * E + lane] = acc[t];
    }
}

// ---------------- Kernel 2: sum partials + sigmoid + top-8 ----------------
__global__ __launch_bounds__(256)
void topk_kernel(const float* __restrict__ part, float* __restrict__ out, int S) {
    __shared__ float lg[32][E + 1];

    const int tid = threadIdx.x;
    const int tok0 = blockIdx.x * 32;
    const size_t base = (size_t)tok0 * E;

    const int f = tid * 8;
    float4 v0 = make_float4(0.f, 0.f, 0.f, 0.f);
    float4 v1 = make_float4(0.f, 0.f, 0.f, 0.f);
    for (int s = 0; s < S; ++s) {
        const float4* p = reinterpret_cast<const float4*>(
            part + (size_t)s * T_TOTAL * E + base + f);
        const float4 a = p[0];
        const float4 b = p[1];
        v0.x += a.x; v0.y += a.y; v0.z += a.z; v0.w += a.w;
        v1.x += b.x; v1.y += b.y; v1.z += b.z; v1.w += b.w;
    }
    {
        const int t = f >> 6;
        const int e = f & 63;
        lg[t][e + 0] = v0.x; lg[t][e + 1] = v0.y; lg[t][e + 2] = v0.z; lg[t][e + 3] = v0.w;
        lg[t][e + 4] = v1.x; lg[t][e + 5] = v1.y; lg[t][e + 6] = v1.z; lg[t][e + 7] = v1.w;
    }
    __syncthreads();

    if (tid < 32) {
        const int t = tid;
        float bv[TOPK];
        int   bi[TOPK];
#pragma unroll
        for (int j = 0; j < TOPK; ++j) { bv[j] = -INFINITY; bi[j] = 0; }

        for (int e = 0; e < E; ++e) {
            const float v = lg[t][e];
            if (v > bv[TOPK - 1]) {
#pragma unroll
                for (int j = TOPK - 1; j > 0; --j) {
                    const bool gt = v > bv[j];
                    const bool gtp = v > bv[j - 1];
                    const float nv = gt ? (gtp ? bv[j - 1] : v) : bv[j];
                    const int   ni = gt ? (gtp ? bi[j - 1] : e) : bi[j];
                    bv[j] = nv; bi[j] = ni;
                }
                if (v > bv[0]) { bv[0] = v; bi[0] = e; }
            }
        }

        float wv[TOPK];
        float wsum = 0.f;
#pragma unroll
        for (int j = 0; j < TOPK; ++j) {
            wv[j] = 1.f / (1.f + expf(-bv[j]));
            wsum += wv[j];
        }
        const float inv = 1.f / fmaxf(wsum, 1e-12f);

        const int tg = tok0 + t;
#pragma unroll
        for (int j = 0; j < TOPK; ++j) {
            out[(size_t)tg * TOPK + j] = wv[j] * inv;
        }
#pragma unroll
        for (int j = 0; j < TOPK; ++j) {
            out[(size_t)T_TOTAL * TOPK + (size_t)tg * TOPK + j] = (float)bi[j];
        }
    }
}

extern "C" void kernel_launch(void* const* d_in, const int* in_sizes, int n_in,
                              void* d_out, int out_size, void* d_ws, size_t ws_size,
                              hipStream_t stream) {
    const float* x = (const float*)d_in[0];
    const float* w = (const float*)d_in[1];
    float* out = (float*)d_out;
    float* part = (float*)d_ws;

    int S = 4;
    if (ws_size < (size_t)4 * T_TOTAL * E * sizeof(float)) {
        S = (ws_size >= (size_t)2 * T_TOTAL * E * sizeof(float)) ? 2 : 1;
    }
    const int dchunk = D_TOTAL / S;

    dim3 g1(T_TOTAL / TB, S);
    gemm_logits<<<g1, 256, 0, stream>>>(x, w, part, dchunk);
    topk_kernel<<<T_TOTAL / 32, 256, 0, stream>>>(part, out, S);
}

// Round 3
// 69.283 us; speedup vs baseline: 2.6054x; 2.6054x over previous
//
#include <hip/hip_runtime.h>
#include <math.h>

#define T_TOTAL 8192
#define D_TOTAL 4096
#define E 64
#define TOPK 8
#define NKB (D_TOTAL / 32)     // 128 k-blocks of 32

typedef short short8 __attribute__((ext_vector_type(8)));
typedef float f32x4 __attribute__((ext_vector_type(4)));

// split fp32 -> 3 bf16 terms (truncation; residuals exact by Sterbenz)
__device__ __forceinline__ void split3(const float* v8, short8& h, short8& m, short8& l) {
#pragma unroll
    for (int j = 0; j < 8; ++j) {
        const float f = v8[j];
        const unsigned u = __float_as_uint(f);
        const unsigned hu = u & 0xffff0000u;
        const float r1 = f - __uint_as_float(hu);
        const unsigned mu = __float_as_uint(r1) & 0xffff0000u;
        const float r2 = r1 - __uint_as_float(mu);
        const unsigned lu = __float_as_uint(r2);
        h[j] = (short)(hu >> 16);
        m[j] = (short)(mu >> 16);
        l[j] = (short)(lu >> 16);
    }
}

// ---------------- Prep: w -> frag-ordered bf16 split arrays ----------------
// Bfrag index: (kb*4 + nt)*64 + lane ; element j holds B[k+j][col] = w[e][k+j]
__global__ __launch_bounds__(256)
void prep_w(const float* __restrict__ w, short8* __restrict__ Bh,
            short8* __restrict__ Bm, short8* __restrict__ Bl) {
    const int t = blockIdx.x * 256 + threadIdx.x;   // [0, NKB*4*64)
    const int lane = t & 63;
    const int nt = (t >> 6) & 3;
    const int kb = t >> 8;
    const int e = nt * 16 + (lane & 15);
    const int k = kb * 32 + (lane >> 4) * 8;

    const float* src = w + (size_t)e * D_TOTAL + k;
    float v[8];
    *reinterpret_cast<float4*>(&v[0]) = *reinterpret_cast<const float4*>(src);
    *reinterpret_cast<float4*>(&v[4]) = *reinterpret_cast<const float4*>(src + 4);

    short8 h, m, l;
    split3(v, h, m, l);
    Bh[t] = h; Bm[t] = m; Bl[t] = l;
}

// ---------------- GEMM: logits partials via bf16-split MFMA ----------------
// wave = 32 rows (2 M-subtiles) x 64 experts (4 N-tiles). No LDS, no barriers.
// grid: (T/128, S); block = 4 waves, each wave an independent 32-row strip.
__global__ __launch_bounds__(256)
void gemm_mfma(const float* __restrict__ x,
               const short8* __restrict__ Bh, const short8* __restrict__ Bm,
               const short8* __restrict__ Bl,
               float* __restrict__ part, int dchunk) {
    const int tid = threadIdx.x;
    const int lane = tid & 63;
    const int wv = tid >> 6;
    const int tok0 = (blockIdx.x * 4 + wv) * 32;
    const int s = blockIdx.y;
    const int k0 = s * dchunk;

    const int row = lane & 15;
    const int kq = lane >> 4;          // 0..3 -> k offset kq*8

    const float* xb = x + (size_t)(tok0 + row) * D_TOTAL + kq * 8;

    f32x4 acc[2][4];
#pragma unroll
    for (int m = 0; m < 2; ++m)
#pragma unroll
        for (int n = 0; n < 4; ++n) acc[m][n] = (f32x4){0.f, 0.f, 0.f, 0.f};

    const int nkb = dchunk >> 5;
    for (int kb = 0; kb < nkb; ++kb) {
        const int k = k0 + kb * 32;
        const int gkb = k >> 5;

        // B fragments: 12 coalesced 16B loads (L2-resident)
        short8 bh[4], bm[4], bl[4];
#pragma unroll
        for (int nt = 0; nt < 4; ++nt) {
            const size_t bi = (size_t)(gkb * 4 + nt) * 64 + lane;
            bh[nt] = Bh[bi];
            bm[nt] = Bm[bi];
            bl[nt] = Bl[bi];
        }

#pragma unroll
        for (int m = 0; m < 2; ++m) {
            const float* ap = xb + (size_t)(m * 16) * D_TOTAL + k;
            float av[8];
            *reinterpret_cast<float4*>(&av[0]) = *reinterpret_cast<const float4*>(ap);
            *reinterpret_cast<float4*>(&av[4]) = *reinterpret_cast<const float4*>(ap + 4);

            short8 ah, am_, al;
            split3(av, ah, am_, al);

#pragma unroll
            for (int nt = 0; nt < 4; ++nt) {
                f32x4 c = acc[m][nt];
                c = __builtin_amdgcn_mfma_f32_16x16x32_bf16(ah,  bh[nt], c, 0, 0, 0);
                c = __builtin_amdgcn_mfma_f32_16x16x32_bf16(ah,  bm[nt], c, 0, 0, 0);
                c = __builtin_amdgcn_mfma_f32_16x16x32_bf16(am_, bh[nt], c, 0, 0, 0);
                c = __builtin_amdgcn_mfma_f32_16x16x32_bf16(am_, bm[nt], c, 0, 0, 0);
                c = __builtin_amdgcn_mfma_f32_16x16x32_bf16(ah,  bl[nt], c, 0, 0, 0);
                c = __builtin_amdgcn_mfma_f32_16x16x32_bf16(al,  bh[nt], c, 0, 0, 0);
                c = __builtin_amdgcn_mfma_f32_16x16x32_bf16(am_, bl[nt], c, 0, 0, 0);
                c = __builtin_amdgcn_mfma_f32_16x16x32_bf16(al,  bm[nt], c, 0, 0, 0);
                acc[m][nt] = c;
            }
        }
    }

    // epilogue: part[s][tok][e]; C/D: col = lane&15, row = (lane>>4)*4 + r
    float* pb = part + ((size_t)s * T_TOTAL + tok0) * E;
#pragma unroll
    for (int m = 0; m < 2; ++m) {
#pragma unroll
        for (int nt = 0; nt < 4; ++nt) {
            const int e = nt * 16 + (lane & 15);
#pragma unroll
            for (int r = 0; r < 4; ++r) {
                const int trow = m * 16 + (lane >> 4) * 4 + r;
                pb[(size_t)trow * E + e] = acc[m][nt][r];
            }
        }
    }
}

// ---------------- sum partials + sigmoid + top-8 ----------------
__global__ __launch_bounds__(256)
void topk_kernel(const float* __restrict__ part, float* __restrict__ out, int S) {
    __shared__ float lg[32][E + 1];

    const int tid = threadIdx.x;
    const int tok0 = blockIdx.x * 32;
    const size_t base = (size_t)tok0 * E;

    const int f = tid * 8;
    float4 v0 = make_float4(0.f, 0.f, 0.f, 0.f);
    float4 v1 = make_float4(0.f, 0.f, 0.f, 0.f);
    for (int s = 0; s < S; ++s) {
        const float4* p = reinterpret_cast<const float4*>(
            part + (size_t)s * T_TOTAL * E + base + f);
        const float4 a = p[0];
        const float4 b = p[1];
        v0.x += a.x; v0.y += a.y; v0.z += a.z; v0.w += a.w;
        v1.x += b.x; v1.y += b.y; v1.z += b.z; v1.w += b.w;
    }
    {
        const int t = f >> 6;
        const int e = f & 63;
        lg[t][e + 0] = v0.x; lg[t][e + 1] = v0.y; lg[t][e + 2] = v0.z; lg[t][e + 3] = v0.w;
        lg[t][e + 4] = v1.x; lg[t][e + 5] = v1.y; lg[t][e + 6] = v1.z; lg[t][e + 7] = v1.w;
    }
    __syncthreads();

    if (tid < 32) {
        const int t = tid;
        float bv[TOPK];
        int   bi[TOPK];
#pragma unroll
        for (int j = 0; j < TOPK; ++j) { bv[j] = -INFINITY; bi[j] = 0; }

        for (int e = 0; e < E; ++e) {
            const float v = lg[t][e];
            if (v > bv[TOPK - 1]) {
#pragma unroll
                for (int j = TOPK - 1; j > 0; --j) {
                    const bool gt = v > bv[j];
                    const bool gtp = v > bv[j - 1];
                    const float nv = gt ? (gtp ? bv[j - 1] : v) : bv[j];
                    const int   ni = gt ? (gtp ? bi[j - 1] : e) : bi[j];
                    bv[j] = nv; bi[j] = ni;
                }
                if (v > bv[0]) { bv[0] = v; bi[0] = e; }
            }
        }

        float wv[TOPK];
        float wsum = 0.f;
#pragma unroll
        for (int j = 0; j < TOPK; ++j) {
            wv[j] = 1.f / (1.f + expf(-bv[j]));
            wsum += wv[j];
        }
        const float inv = 1.f / fmaxf(wsum, 1e-12f);

        const int tg = tok0 + t;
#pragma unroll
        for (int j = 0; j < TOPK; ++j) {
            out[(size_t)tg * TOPK + j] = wv[j] * inv;
        }
#pragma unroll
        for (int j = 0; j < TOPK; ++j) {
            out[(size_t)T_TOTAL * TOPK + (size_t)tg * TOPK + j] = (float)bi[j];
        }
    }
}

extern "C" void kernel_launch(void* const* d_in, const int* in_sizes, int n_in,
                              void* d_out, int out_size, void* d_ws, size_t ws_size,
                              hipStream_t stream) {
    const float* x = (const float*)d_in[0];
    const float* w = (const float*)d_in[1];
    float* out = (float*)d_out;

    // pick S (K-split) by workspace: partials S*2MB + B frag arrays 1.5MB
    const size_t partial_elems_per_s = (size_t)T_TOTAL * E;
    const size_t frag_bytes = (size_t)3 * NKB * 4 * 64 * sizeof(short8);
    int S = 8;
    while (S > 1 && (size_t)S * partial_elems_per_s * sizeof(float) + frag_bytes > ws_size)
        S >>= 1;
    const int dchunk = D_TOTAL / S;

    float* part = (float*)d_ws;
    short8* Bh = (short8*)((char*)d_ws + (size_t)S * partial_elems_per_s * sizeof(float));
    short8* Bm = Bh + (size_t)NKB * 4 * 64;
    short8* Bl = Bm + (size_t)NKB * 4 * 64;

    prep_w<<<NKB * 4 * 64 / 256, 256, 0, stream>>>(w, Bh, Bm, Bl);
    dim3 g(T_TOTAL / 128, S);
    gemm_mfma<<<g, 256, 0, stream>>>(x, Bh, Bm, Bl, part, dchunk);
    topk_kernel<<<T_TOTAL / 32, 256, 0, stream>>>(part, out, S);
}

// Round 4
// 56.437 us; speedup vs baseline: 3.1984x; 1.2276x over previous
//
#include <hip/hip_runtime.h>
#include <math.h>

#define T_TOTAL 8192
#define D_TOTAL 4096
#define E 64
#define TOPK 8
#define NKB (D_TOTAL / 32)     // 128 k-blocks of 32

typedef short short8 __attribute__((ext_vector_type(8)));
typedef float f32x4 __attribute__((ext_vector_type(4)));

// split fp32 -> 3 bf16 terms (truncation; residuals exact by Sterbenz)
__device__ __forceinline__ void split3(const float* v8, short8& h, short8& m, short8& l) {
#pragma unroll
    for (int j = 0; j < 8; ++j) {
        const float f = v8[j];
        const unsigned u = __float_as_uint(f);
        const unsigned hu = u & 0xffff0000u;
        const float r1 = f - __uint_as_float(hu);
        const unsigned mu = __float_as_uint(r1) & 0xffff0000u;
        const float r2 = r1 - __uint_as_float(mu);
        const unsigned lu = __float_as_uint(r2);
        h[j] = (short)(hu >> 16);
        m[j] = (short)(mu >> 16);
        l[j] = (short)(lu >> 16);
    }
}

// ---------------- Prep: w -> frag-ordered bf16 split arrays ----------------
// Bfrag index: (kb*4 + nt)*64 + lane ; element j holds B[k+j][col] = w[e][k+j]
__global__ __launch_bounds__(256)
void prep_w(const float* __restrict__ w, short8* __restrict__ Bh,
            short8* __restrict__ Bm, short8* __restrict__ Bl) {
    const int t = blockIdx.x * 256 + threadIdx.x;   // [0, NKB*4*64)
    const int lane = t & 63;
    const int nt = (t >> 6) & 3;
    const int kb = t >> 8;
    const int e = nt * 16 + (lane & 15);
    const int k = kb * 32 + (lane >> 4) * 8;

    const float* src = w + (size_t)e * D_TOTAL + k;
    float v[8];
    *reinterpret_cast<float4*>(&v[0]) = *reinterpret_cast<const float4*>(src);
    *reinterpret_cast<float4*>(&v[4]) = *reinterpret_cast<const float4*>(src + 4);

    short8 h, m, l;
    split3(v, h, m, l);
    Bh[t] = h; Bm[t] = m; Bl[t] = l;
}

// ---------------- Fused: GEMM (bf16-split MFMA) + reduce + sigmoid + top-8 ----
// Block = 1024 threads (16 waves) per 32 tokens. Wave w covers K-chunk
// [w*256, (w+1)*256). LDS tree-reduce combines the 16 K-partials, wave 0
// finishes with sigmoid + top-8. grid = 256 blocks = 1/CU (4 waves/SIMD).
__global__ __launch_bounds__(1024, 4)
void fused_router(const float* __restrict__ x,
                  const short8* __restrict__ Bh, const short8* __restrict__ Bm,
                  const short8* __restrict__ Bl,
                  float* __restrict__ out) {
    __shared__ float red[8 * 32 * 64];   // 64 KB: 8 tiles of [j<32][lane<64]

    const int tid = threadIdx.x;
    const int lane = tid & 63;
    const int wv = tid >> 6;
    const int tok0 = blockIdx.x * 32;

    const int row = lane & 15;
    const int kq = lane >> 4;            // k offset kq*8 within 32-k block

    const float* xb = x + (size_t)(tok0 + row) * D_TOTAL + kq * 8;

    f32x4 acc[2][4];
#pragma unroll
    for (int m = 0; m < 2; ++m)
#pragma unroll
        for (int n = 0; n < 4; ++n) acc[m][n] = (f32x4){0.f, 0.f, 0.f, 0.f};

    const int kbase = wv * (D_TOTAL / 16);   // 256-wide K chunk per wave

    for (int kb = 0; kb < 8; ++kb) {
        const int k = kbase + kb * 32;
        const int gkb = k >> 5;

        // B fragments: 12 coalesced 16B loads (L2-resident after first touch)
        short8 bh[4], bm[4], bl[4];
#pragma unroll
        for (int nt = 0; nt < 4; ++nt) {
            const size_t bi = (size_t)(gkb * 4 + nt) * 64 + lane;
            bh[nt] = Bh[bi];
            bm[nt] = Bm[bi];
            bl[nt] = Bl[bi];
        }

#pragma unroll
        for (int m = 0; m < 2; ++m) {
            const float* ap = xb + (size_t)(m * 16) * D_TOTAL + k;
            float av[8];
            *reinterpret_cast<float4*>(&av[0]) = *reinterpret_cast<const float4*>(ap);
            *reinterpret_cast<float4*>(&av[4]) = *reinterpret_cast<const float4*>(ap + 4);

            short8 ah, am_, al;
            split3(av, ah, am_, al);

#pragma unroll
            for (int nt = 0; nt < 4; ++nt) {
                f32x4 c = acc[m][nt];
                c = __builtin_amdgcn_mfma_f32_16x16x32_bf16(ah,  bh[nt], c, 0, 0, 0);
                c = __builtin_amdgcn_mfma_f32_16x16x32_bf16(ah,  bm[nt], c, 0, 0, 0);
                c = __builtin_amdgcn_mfma_f32_16x16x32_bf16(am_, bh[nt], c, 0, 0, 0);
                c = __builtin_amdgcn_mfma_f32_16x16x32_bf16(am_, bm[nt], c, 0, 0, 0);
                c = __builtin_amdgcn_mfma_f32_16x16x32_bf16(ah,  bl[nt], c, 0, 0, 0);
                c = __builtin_amdgcn_mfma_f32_16x16x32_bf16(al,  bh[nt], c, 0, 0, 0);
                c = __builtin_amdgcn_mfma_f32_16x16x32_bf16(am_, bl[nt], c, 0, 0, 0);
                c = __builtin_amdgcn_mfma_f32_16x16x32_bf16(al,  bm[nt], c, 0, 0, 0);
                acc[m][nt] = c;
            }
        }
    }

    // ---- LDS tree reduce across 16 waves (lane-major slots: conflict-free) ----
#pragma unroll
    for (int half = 8; half >= 1; half >>= 1) {
        if (wv >= half && wv < 2 * half) {
            float* s = &red[(size_t)(wv - half) * 32 * 64 + lane];
#pragma unroll
            for (int m = 0; m < 2; ++m)
#pragma unroll
                for (int nt = 0; nt < 4; ++nt)
#pragma unroll
                    for (int r = 0; r < 4; ++r)
                        s[(m * 16 + nt * 4 + r) * 64] = acc[m][nt][r];
        }
        __syncthreads();
        if (wv < half) {
            const float* s = &red[(size_t)wv * 32 * 64 + lane];
#pragma unroll
            for (int m = 0; m < 2; ++m)
#pragma unroll
                for (int nt = 0; nt < 4; ++nt)
#pragma unroll
                    for (int r = 0; r < 4; ++r)
                        acc[m][nt][r] += s[(m * 16 + nt * 4 + r) * 64];
        }
        __syncthreads();
    }

    // ---- wave 0 lays out logits [t][e] for top-k ----
    if (wv == 0) {
        // C/D layout: col = lane&15, row = (lane>>4)*4 + r
#pragma unroll
        for (int m = 0; m < 2; ++m)
#pragma unroll
            for (int nt = 0; nt < 4; ++nt)
#pragma unroll
                for (int r = 0; r < 4; ++r) {
                    const int t = m * 16 + (lane >> 4) * 4 + r;
                    const int e = nt * 16 + (lane & 15);
                    red[t * 65 + e] = acc[m][nt][r];
                }
    }
    __syncthreads();

    if (tid < 32) {
        const int t = tid;
        float bv[TOPK];
        int   bi[TOPK];
#pragma unroll
        for (int j = 0; j < TOPK; ++j) { bv[j] = -INFINITY; bi[j] = 0; }

        for (int e = 0; e < E; ++e) {
            const float v = red[t * 65 + e];
            if (v > bv[TOPK - 1]) {
#pragma unroll
                for (int j = TOPK - 1; j > 0; --j) {
                    const bool gt = v > bv[j];
                    const bool gtp = v > bv[j - 1];
                    const float nv = gt ? (gtp ? bv[j - 1] : v) : bv[j];
                    const int   ni = gt ? (gtp ? bi[j - 1] : e) : bi[j];
                    bv[j] = nv; bi[j] = ni;
                }
                if (v > bv[0]) { bv[0] = v; bi[0] = e; }
            }
        }

        float wv_[TOPK];
        float wsum = 0.f;
#pragma unroll
        for (int j = 0; j < TOPK; ++j) {
            wv_[j] = 1.f / (1.f + expf(-bv[j]));
            wsum += wv_[j];
        }
        const float inv = 1.f / fmaxf(wsum, 1e-12f);

        const int tg = tok0 + t;
#pragma unroll
        for (int j = 0; j < TOPK; ++j) {
            out[(size_t)tg * TOPK + j] = wv_[j] * inv;
        }
#pragma unroll
        for (int j = 0; j < TOPK; ++j) {
            out[(size_t)T_TOTAL * TOPK + (size_t)tg * TOPK + j] = (float)bi[j];
        }
    }
}

extern "C" void kernel_launch(void* const* d_in, const int* in_sizes, int n_in,
                              void* d_out, int out_size, void* d_ws, size_t ws_size,
                              hipStream_t stream) {
    const float* x = (const float*)d_in[0];
    const float* w = (const float*)d_in[1];
    float* out = (float*)d_out;

    short8* Bh = (short8*)d_ws;
    short8* Bm = Bh + (size_t)NKB * 4 * 64;
    short8* Bl = Bm + (size_t)NKB * 4 * 64;

    prep_w<<<NKB * 4 * 64 / 256, 256, 0, stream>>>(w, Bh, Bm, Bl);
    fused_router<<<T_TOTAL / 32, 1024, 0, stream>>>(x, Bh, Bm, Bl, out);
}

// Round 5
// 51.388 us; speedup vs baseline: 3.5127x; 1.0983x over previous
//
#include <hip/hip_runtime.h>
#include <math.h>

#define T_TOTAL 8192
#define D_TOTAL 4096
#define E 64
#define TOPK 8
#define NKB (D_TOTAL / 32)     // 128 k-blocks of 32

typedef short short8 __attribute__((ext_vector_type(8)));
typedef float f32x4 __attribute__((ext_vector_type(4)));

// split fp32 -> 3 bf16 terms (truncation; residuals exact)
__device__ __forceinline__ void split3(const float* v8, short8& h, short8& m, short8& l) {
#pragma unroll
    for (int j = 0; j < 8; ++j) {
        const float f = v8[j];
        const unsigned u = __float_as_uint(f);
        const unsigned hu = u & 0xffff0000u;
        const float r1 = f - __uint_as_float(hu);
        const unsigned mu = __float_as_uint(r1) & 0xffff0000u;
        const float r2 = r1 - __uint_as_float(mu);
        const unsigned lu = __float_as_uint(r2);
        h[j] = (short)(hu >> 16);
        m[j] = (short)(mu >> 16);
        l[j] = (short)(lu >> 16);
    }
}

// ---------------- Prep: w -> frag-ordered bf16 split arrays ----------------
__global__ __launch_bounds__(256)
void prep_w(const float* __restrict__ w, short8* __restrict__ Bh,
            short8* __restrict__ Bm, short8* __restrict__ Bl) {
    const int t = blockIdx.x * 256 + threadIdx.x;   // [0, NKB*4*64)
    const int lane = t & 63;
    const int nt = (t >> 6) & 3;
    const int kb = t >> 8;
    const int e = nt * 16 + (lane & 15);
    const int k = kb * 32 + (lane >> 4) * 8;

    const float* src = w + (size_t)e * D_TOTAL + k;
    float v[8];
    *reinterpret_cast<float4*>(&v[0]) = *reinterpret_cast<const float4*>(src);
    *reinterpret_cast<float4*>(&v[4]) = *reinterpret_cast<const float4*>(src + 4);

    short8 h, m, l;
    split3(v, h, m, l);
    Bh[t] = h; Bm[t] = m; Bl[t] = l;
}

#define LOADX(DST, K) {                                                              \
    const float* ap0 = xb + (K);                                                     \
    *reinterpret_cast<float4*>(&(DST)[0])  = *reinterpret_cast<const float4*>(ap0);  \
    *reinterpret_cast<float4*>(&(DST)[4])  = *reinterpret_cast<const float4*>(ap0 + 4); \
    const float* ap1 = ap0 + 16 * D_TOTAL;                                           \
    *reinterpret_cast<float4*>(&(DST)[8])  = *reinterpret_cast<const float4*>(ap1);  \
    *reinterpret_cast<float4*>(&(DST)[12]) = *reinterpret_cast<const float4*>(ap1 + 4); \
}

// ---------------- Fused: GEMM (bf16-split MFMA) + reduce + sigmoid + top-8 ----
// 16 waves / 32 tokens / block; wave w covers K-chunk [w*256,(w+1)*256).
// x double-buffered in regs (prefetch 1 kb ahead); 6 MFMA per (m,nt).
__global__ __launch_bounds__(1024, 4)
void fused_router(const float* __restrict__ x,
                  const short8* __restrict__ Bh, const short8* __restrict__ Bm,
                  const short8* __restrict__ Bl,
                  float* __restrict__ out) {
    __shared__ float tiles[8 * 2048];   // 64 KB
    __shared__ float fin[2048];         // 8 KB: logits [t][e]

    const int tid = threadIdx.x;
    const int lane = tid & 63;
    const int wv = tid >> 6;
    const int tok0 = blockIdx.x * 32;

    const int row = lane & 15;
    const int kq = lane >> 4;

    const float* xb = x + (size_t)(tok0 + row) * D_TOTAL + kq * 8;

    f32x4 acc[2][4];
#pragma unroll
    for (int m = 0; m < 2; ++m)
#pragma unroll
        for (int n = 0; n < 4; ++n) acc[m][n] = (f32x4){0.f, 0.f, 0.f, 0.f};

    const int kbase = wv * 256;

    float xbuf[2][16];
    LOADX(xbuf[0], kbase);

#pragma unroll
    for (int kb = 0; kb < 8; ++kb) {
        const int k = kbase + kb * 32;
        const int gkb = k >> 5;

        // B fragments for this kb (L2-resident)
        short8 bh[4], bm[4], bl[4];
#pragma unroll
        for (int nt = 0; nt < 4; ++nt) {
            const size_t bi = (size_t)(gkb * 4 + nt) * 64 + lane;
            bh[nt] = Bh[bi];
            bm[nt] = Bm[bi];
            bl[nt] = Bl[bi];
        }

        // prefetch next kb's x while this kb computes
        if (kb < 7) LOADX(xbuf[(kb + 1) & 1], k + 32);

#pragma unroll
        for (int m = 0; m < 2; ++m) {
            short8 ah, am_, al;
            split3(&xbuf[kb & 1][m * 8], ah, am_, al);
#pragma unroll
            for (int nt = 0; nt < 4; ++nt) {
                f32x4 c = acc[m][nt];
                c = __builtin_amdgcn_mfma_f32_16x16x32_bf16(ah,  bh[nt], c, 0, 0, 0);
                c = __builtin_amdgcn_mfma_f32_16x16x32_bf16(ah,  bm[nt], c, 0, 0, 0);
                c = __builtin_amdgcn_mfma_f32_16x16x32_bf16(am_, bh[nt], c, 0, 0, 0);
                c = __builtin_amdgcn_mfma_f32_16x16x32_bf16(am_, bm[nt], c, 0, 0, 0);
                c = __builtin_amdgcn_mfma_f32_16x16x32_bf16(ah,  bl[nt], c, 0, 0, 0);
                c = __builtin_amdgcn_mfma_f32_16x16x32_bf16(al,  bh[nt], c, 0, 0, 0);
                acc[m][nt] = c;
            }
        }
    }

    // ---- reduce 16 wave-partials: fold 16->8 in LDS, then flat 8-way sum ----
    if (wv >= 8) {
        float* s = &tiles[(size_t)(wv - 8) * 2048 + lane];
#pragma unroll
        for (int m = 0; m < 2; ++m)
#pragma unroll
            for (int nt = 0; nt < 4; ++nt)
#pragma unroll
                for (int r = 0; r < 4; ++r)
                    s[(m * 16 + nt * 4 + r) * 64] = acc[m][nt][r];
    }
    __syncthreads();
    if (wv < 8) {
        float* s = &tiles[(size_t)wv * 2048 + lane];
#pragma unroll
        for (int m = 0; m < 2; ++m)
#pragma unroll
            for (int nt = 0; nt < 4; ++nt)
#pragma unroll
                for (int r = 0; r < 4; ++r) {
                    const int j = (m * 16 + nt * 4 + r) * 64;
                    s[j] = acc[m][nt][r] + s[j];
                }
    }
    __syncthreads();

    // flat sum over 8 tiles; each thread owns values tid and tid+1024
    {
        float s0 = 0.f, s1 = 0.f;
#pragma unroll
        for (int w2 = 0; w2 < 8; ++w2) {
            s0 += tiles[w2 * 2048 + tid];
            s1 += tiles[w2 * 2048 + 1024 + tid];
        }
        // v = j*64 + lane', j = m*16+nt*4+r, lane' = kq*16+col
        const int j = tid >> 6, ln = tid & 63;
        const int t = (ln >> 4) * 4 + (j & 3);          // m=0 part
        const int e = ((j >> 2) & 3) * 16 + (ln & 15);
        fin[t * 64 + e] = s0;
        fin[(t + 16) * 64 + e] = s1;                     // m=1 part
    }
    __syncthreads();

    // ---- per-wave top-8: wave wv handles tokens 2*wv, 2*wv+1 ----
#pragma unroll
    for (int rep = 0; rep < 2; ++rep) {
        const int t = wv * 2 + rep;
        float v = fin[t * 64 + lane];
        float wj[TOPK];
        int   ij[TOPK];
        float wsum = 0.f;
#pragma unroll
        for (int j = 0; j < TOPK; ++j) {
            float mx = v;
#pragma unroll
            for (int off = 32; off >= 1; off >>= 1)
                mx = fmaxf(mx, __shfl_xor(mx, off));
            const unsigned long long msk = __ballot(v == mx);
            const int widx = (int)__builtin_ctzll(msk);   // lowest index on ties
            wj[j] = 1.f / (1.f + expf(-mx));
            ij[j] = widx;
            wsum += wj[j];
            if (lane == widx) v = -INFINITY;
        }
        const float inv = 1.f / fmaxf(wsum, 1e-12f);
        const int tg = tok0 + t;
        if (lane == 0) {
#pragma unroll
            for (int j = 0; j < TOPK; ++j)
                out[(size_t)tg * TOPK + j] = wj[j] * inv;
#pragma unroll
            for (int j = 0; j < TOPK; ++j)
                out[(size_t)T_TOTAL * TOPK + (size_t)tg * TOPK + j] = (float)ij[j];
        }
    }
}

extern "C" void kernel_launch(void* const* d_in, const int* in_sizes, int n_in,
                              void* d_out, int out_size, void* d_ws, size_t ws_size,
                              hipStream_t stream) {
    const float* x = (const float*)d_in[0];
    const float* w = (const float*)d_in[1];
    float* out = (float*)d_out;

    short8* Bh = (short8*)d_ws;
    short8* Bm = Bh + (size_t)NKB * 4 * 64;
    short8* Bl = Bm + (size_t)NKB * 4 * 64;

    prep_w<<<NKB * 4 * 64 / 256, 256, 0, stream>>>(w, Bh, Bm, Bl);
    fused_router<<<T_TOTAL / 32, 1024, 0, stream>>>(x, Bh, Bm, Bl, out);
}